// Round 5
// baseline (122.960 us; speedup 1.0000x reference)
//
#include <hip/hip_runtime.h>
#include <hip/hip_bf16.h>
#include <cstdint>

#define B_ 8
#define N_ 512
#define D_ 256
#define E_ 16384
#define H_ 256

#define SA_STRIDE 56
#define SB_STRIDE 56

using bf16x8 = __attribute__((ext_vector_type(8))) short;
using f32x4  = __attribute__((ext_vector_type(4))) float;

__device__ inline unsigned short f2bf(float f) {
    union { float f; unsigned u; } v; v.f = f;
    unsigned u = v.u;
    return (unsigned short)((u + 0x7fffu + ((u >> 16) & 1u)) >> 16);  // RNE
}

// blocks 0-31: transpose W1 halves -> W1T (512 n-rows x 256 k) bf16.
// block 32: counting-sort the (shared-across-batch) edge list by src:
//   gStarts[513] bucket offsets, gSorted[16384] dst values in src order.
__global__ __launch_bounds__(256)
void prep_k(const float* __restrict__ W1, const int* __restrict__ eidx,
            unsigned short* __restrict__ W1T,
            int* __restrict__ gStarts, int* __restrict__ gSorted) {
    __shared__ float tile[64][65];
    __shared__ int hist[4][512];
    __shared__ int sc[2][512];
    __shared__ int cursor[512];

    const int tb = blockIdx.x, t = threadIdx.x;

    if (tb < 32) {
        const int h   = tb >> 4;
        const int rem = tb & 15;
        const int tk  = (rem >> 2) * 64;
        const int tn  = (rem & 3) * 64;
        const float* Wh = W1 + (size_t)h * 256 * 256;
        const int c = t & 63, r0 = t >> 6;
#pragma unroll
        for (int i = 0; i < 16; i++) {
            int r = r0 + i * 4;
            tile[r][c] = Wh[(size_t)(tk + r) * 256 + tn + c];
        }
        __syncthreads();
#pragma unroll
        for (int i = 0; i < 16; i++) {
            int rn = r0 + i * 4;
            W1T[(size_t)(h * 256 + tn + rn) * 256 + tk + c] = f2bf(tile[c][rn]);
        }
        return;
    }

    // ---- sort block ----
    const int w = t >> 6;
    for (int i = t; i < 4 * 512; i += 256) ((int*)hist)[i] = 0;
    __syncthreads();
    for (int i = 0; i < 64; i++) {
        int s = eidx[t + 256 * i];
        atomicAdd(&hist[w][s], 1);
    }
    __syncthreads();
    for (int i = t; i < 512; i += 256)
        sc[0][i] = hist[0][i] + hist[1][i] + hist[2][i] + hist[3][i];
    __syncthreads();
    int cur = 0;
    for (int off = 1; off < 512; off <<= 1) {
#pragma unroll
        for (int k = 0; k < 2; k++) {
            int i = t + 256 * k;
            int v = sc[cur][i];
            if (i >= off) v += sc[cur][i - off];
            sc[cur ^ 1][i] = v;
        }
        __syncthreads();
        cur ^= 1;
    }
    for (int i = t; i < 512; i += 256) {
        int st = (i == 0) ? 0 : sc[cur][i - 1];
        cursor[i]  = st;
        gStarts[i] = st;
    }
    if (t == 0) gStarts[512] = E_;
    __syncthreads();
    for (int i = 0; i < 64; i++) {
        int e = t + 256 * i;
        int s = eidx[e];
        int d = eidx[E_ + e];
        int pos = atomicAdd(&cursor[s], 1);
        gSorted[pos] = d;
    }
}

// P (4096,512) bf16: cols 0-255 = U + b1 (bias folded), cols 256-511 = V.
// Also zeroes d_out (each of 128 blocks clears 64 KB).
__global__ __launch_bounds__(256)
void node_gemm(const float* __restrict__ feat,
               const unsigned short* __restrict__ W1T,
               const float* __restrict__ b1,
               unsigned short* __restrict__ P,
               float4* __restrict__ out4) {
    __shared__ unsigned short sA[64 * SA_STRIDE];
    __shared__ unsigned short sB[256 * SB_STRIDE];

    const int t  = threadIdx.x;
    const int bm = blockIdx.x >> 1;
    const int bn = blockIdx.x & 1;
    const int m0 = bm * 64;

    {
        float4 z = make_float4(0.f, 0.f, 0.f, 0.f);
        float4* oz = out4 + (size_t)blockIdx.x * 4096 + t;
#pragma unroll
        for (int i = 0; i < 16; i++) oz[i * 256] = z;
    }

    const int arow = t >> 2;
    const int akg  = (t & 3) * 8;
    const float* pA = feat + (size_t)(m0 + arow) * 256;
    const unsigned short* pB = W1T + (size_t)(bn * 256 + t) * 256;

    const int wave = t >> 6, lane = t & 63, l15 = lane & 15, quad = lane >> 4;

    f32x4 acc[4][4];
#pragma unroll
    for (int rm = 0; rm < 4; rm++)
#pragma unroll
        for (int cn = 0; cn < 4; cn++)
            acc[rm][cn] = (f32x4){0.f, 0.f, 0.f, 0.f};

    for (int k0 = 0; k0 < 256; k0 += 32) {
        __syncthreads();
        {
            float4 lo = *(const float4*)(pA + k0 + akg);
            float4 hi = *(const float4*)(pA + k0 + akg + 4);
            union { bf16x8 v; unsigned short s[8]; } u;
            u.s[0] = f2bf(lo.x); u.s[1] = f2bf(lo.y); u.s[2] = f2bf(lo.z); u.s[3] = f2bf(lo.w);
            u.s[4] = f2bf(hi.x); u.s[5] = f2bf(hi.y); u.s[6] = f2bf(hi.z); u.s[7] = f2bf(hi.w);
            *(bf16x8*)(sA + arow * SA_STRIDE + akg) = u.v;
        }
        {
            const unsigned short* p = pB + k0;
            uint4 q0 = *(const uint4*)(p);
            uint4 q1 = *(const uint4*)(p + 8);
            uint4 q2 = *(const uint4*)(p + 16);
            uint4 q3 = *(const uint4*)(p + 24);
            *(uint4*)(sB + t * SB_STRIDE +  0) = q0;
            *(uint4*)(sB + t * SB_STRIDE +  8) = q1;
            *(uint4*)(sB + t * SB_STRIDE + 16) = q2;
            *(uint4*)(sB + t * SB_STRIDE + 24) = q3;
        }
        __syncthreads();

        bf16x8 af[4], bfr[4];
#pragma unroll
        for (int rm = 0; rm < 4; rm++)
            af[rm] = *(const bf16x8*)(sA + (rm * 16 + l15) * SA_STRIDE + quad * 8);
#pragma unroll
        for (int cn = 0; cn < 4; cn++)
            bfr[cn] = *(const bf16x8*)(sB + (wave * 64 + cn * 16 + l15) * SB_STRIDE + quad * 8);
#pragma unroll
        for (int rm = 0; rm < 4; rm++)
#pragma unroll
            for (int cn = 0; cn < 4; cn++)
                acc[rm][cn] = __builtin_amdgcn_mfma_f32_16x16x32_bf16(af[rm], bfr[cn], acc[rm][cn], 0, 0, 0);
    }

#pragma unroll
    for (int cn = 0; cn < 4; cn++) {
        int colh = wave * 64 + cn * 16 + l15;
        float bias = (bn == 0) ? b1[colh] : 0.f;
        int col = bn * 256 + colh;
#pragma unroll
        for (int rm = 0; rm < 4; rm++)
#pragma unroll
            for (int r = 0; r < 4; r++) {
                int row = m0 + rm * 16 + quad * 4 + r;
                P[(size_t)row * 512 + col] = f2bf(acc[rm][cn][r] + bias);
            }
    }
}

// 8 bf16 (u,v) pairs -> partial relu-dot (b1 already folded into u)
__device__ inline float dot8nb(uint4 qu, uint4 qv, const float* w2p) {
    unsigned us[4] = {qu.x, qu.y, qu.z, qu.w};
    unsigned vs[4] = {qv.x, qv.y, qv.z, qv.w};
    float p = 0.f;
#pragma unroll
    for (int j = 0; j < 4; j++) {
        float ulo = __uint_as_float(us[j] << 16);
        float uhi = __uint_as_float(us[j] & 0xffff0000u);
        float vlo = __uint_as_float(vs[j] << 16);
        float vhi = __uint_as_float(vs[j] & 0xffff0000u);
        float hlo = fmaxf(ulo + vlo, 0.f);
        float hhi = fmaxf(uhi + vhi, 0.f);
        p = fmaf(hlo, w2p[2 * j],     p);
        p = fmaf(hhi, w2p[2 * j + 1], p);
    }
    return p;
}

// Bucketed edge scoring: 16-lane worker owns (bucket src, offset o); loads
// U'[src] once into regs, streams V[dst] for dsts o, o+8, ... (2-stage pipeline).
__global__ __launch_bounds__(256)
void edge_score(const unsigned short* __restrict__ P,
                const float* __restrict__ W2, const float* __restrict__ b2,
                const int* __restrict__ gStarts, const int* __restrict__ gSorted,
                float* __restrict__ out) {
    const int b     = blockIdx.x & 7;          // XCD-aware batch mapping
    const int chunk = blockIdx.x >> 3;         // 0..255 -> srcs {2c, 2c+1}
    const int lane  = threadIdx.x & 63;
    const int wave  = threadIdx.x >> 6;
    const int g     = lane >> 4;
    const int w     = lane & 15;
    const int wid   = wave * 4 + g;            // 0..15
    const int s     = 2 * chunk + (wid >> 3);  // bucket src
    const int o     = wid & 7;                 // worker offset in bucket

    const int st = gStarts[s], en = gStarts[s + 1];

    float w2r[16];
#pragma unroll
    for (int j = 0; j < 4; j++)
        *(float4*)(w2r + 4 * j) = *(const float4*)(W2 + w * 16 + 4 * j);
    const float b2v = b2[0];

    const unsigned short* Pu = P + ((size_t)b * 512 + s) * 512 + w * 16;
    uint4 u0 = *(const uint4*)(Pu);
    uint4 u1 = *(const uint4*)(Pu + 8);
    const unsigned short* Pv = P + (size_t)b * 512 * 512 + 256 + w * 16;
    float* outb = out + ((size_t)b * 512 + s) * 512;

    int j = st + o;
    int dst0 = 0; uint4 v00 = {}, v01 = {};
    if (j < en) {
        dst0 = gSorted[j];
        const unsigned short* pv = Pv + (size_t)dst0 * 512;
        v00 = *(const uint4*)pv; v01 = *(const uint4*)(pv + 8);
    }
    while (j < en) {
        int jn = j + 8;
        int dst1 = 0; uint4 v10 = {}, v11 = {};
        if (jn < en) {
            dst1 = gSorted[jn];
            const unsigned short* pv = Pv + (size_t)dst1 * 512;
            v10 = *(const uint4*)pv; v11 = *(const uint4*)(pv + 8);
        }
        float p = dot8nb(u0, v00, w2r) + dot8nb(u1, v01, w2r + 8);
        p += __shfl_xor(p, 1);
        p += __shfl_xor(p, 2);
        p += __shfl_xor(p, 4);
        p += __shfl_xor(p, 8);
        if (w == 0) {
            float sv = 1.0f / (1.0f + __expf(-(p + b2v)));
            outb[dst0] = sv;
        }
        dst0 = dst1; v00 = v10; v01 = v11; j = jn;
    }
}

extern "C" void kernel_launch(void* const* d_in, const int* in_sizes, int n_in,
                              void* d_out, int out_size, void* d_ws, size_t ws_size,
                              hipStream_t stream) {
    const float* feat = (const float*)d_in[0];
    const float* W1   = (const float*)d_in[1];
    const float* b1   = (const float*)d_in[2];
    const float* W2   = (const float*)d_in[3];
    const float* b2   = (const float*)d_in[4];
    const int*   eidx = (const int*)d_in[5];
    float* out = (float*)d_out;

    unsigned short* W1T = (unsigned short*)d_ws;                        // 256 KB
    unsigned short* P   = (unsigned short*)((char*)d_ws + (1 << 20));   // 4 MB
    int* gStarts = (int*)((char*)d_ws + (6 << 20));                     // 513 ints
    int* gSorted = (int*)((char*)d_ws + (6 << 20) + 4096);              // 64 KB

    prep_k<<<33, 256, 0, stream>>>(W1, eidx, W1T, gStarts, gSorted);
    node_gemm<<<128, 256, 0, stream>>>(feat, W1T, b1, P, (float4*)out);
    edge_score<<<2048, 256, 0, stream>>>(P, W2, b2, gStarts, gSorted, out);
}

// Round 6
// 97.256 us; speedup vs baseline: 1.2643x; 1.2643x over previous
//
#include <hip/hip_runtime.h>
#include <hip/hip_bf16.h>
#include <cstdint>

#define B_ 8
#define N_ 512
#define D_ 256
#define E_ 16384
#define H_ 256

#define SA_STRIDE 56
#define SB_STRIDE 56
#define BCAP 128   // bucket capacity (mean 32, max ~55 for E=16384 over 512 srcs)

using bf16x8 = __attribute__((ext_vector_type(8))) short;
using f32x4  = __attribute__((ext_vector_type(4))) float;

__device__ inline unsigned short f2bf(float f) {
    union { float f; unsigned u; } v; v.f = f;
    unsigned u = v.u;
    return (unsigned short)((u + 0x7fffu + ((u >> 16) & 1u)) >> 16);  // RNE
}

// blocks 0-31: transpose W1 halves -> W1T (512 n-rows x 256 k) bf16.
// block 32: zero the 512 bucket counters.
__global__ __launch_bounds__(256)
void prep_k(const float* __restrict__ W1, unsigned short* __restrict__ W1T,
            int* __restrict__ gCount) {
    __shared__ float tile[64][65];
    const int tb = blockIdx.x, t = threadIdx.x;
    if (tb == 32) {
        gCount[t] = 0;
        gCount[t + 256] = 0;
        return;
    }
    const int h   = tb >> 4;
    const int rem = tb & 15;
    const int tk  = (rem >> 2) * 64;
    const int tn  = (rem & 3) * 64;
    const float* Wh = W1 + (size_t)h * 256 * 256;
    const int c = t & 63, r0 = t >> 6;
#pragma unroll
    for (int i = 0; i < 16; i++) {
        int r = r0 + i * 4;
        tile[r][c] = Wh[(size_t)(tk + r) * 256 + tn + c];
    }
    __syncthreads();
#pragma unroll
    for (int i = 0; i < 16; i++) {
        int rn = r0 + i * 4;
        W1T[(size_t)(h * 256 + tn + rn) * 256 + tk + c] = f2bf(tile[c][rn]);
    }
}

// blocks 0-127: P (4096,512) bf16 = feat x [W1a|W1b], b1 folded into U half;
//               also zeroes d_out (64 KB per block).
// blocks 128-191: bucket-scatter the edge list (shared across batches):
//               slot = atomicAdd(gCount[src]); gBucket[src*BCAP+slot] = dst.
__global__ __launch_bounds__(256)
void node_gemm(const float* __restrict__ feat,
               const unsigned short* __restrict__ W1T,
               const float* __restrict__ b1,
               const int* __restrict__ eidx,
               unsigned short* __restrict__ P,
               float4* __restrict__ out4,
               int* __restrict__ gCount, int* __restrict__ gBucket) {
    __shared__ unsigned short sA[64 * SA_STRIDE];
    __shared__ unsigned short sB[256 * SB_STRIDE];

    const int t = threadIdx.x;

    if (blockIdx.x >= 128) {
        int e = (blockIdx.x - 128) * 256 + t;
        int s = eidx[e];
        int d = eidx[E_ + e];
        int pos = atomicAdd(&gCount[s], 1);
        gBucket[(s << 7) + pos] = d;
        return;
    }

    const int bm = blockIdx.x >> 1;
    const int bn = blockIdx.x & 1;
    const int m0 = bm * 64;

    {
        float4 z = make_float4(0.f, 0.f, 0.f, 0.f);
        float4* oz = out4 + (size_t)blockIdx.x * 4096 + t;
#pragma unroll
        for (int i = 0; i < 16; i++) oz[i * 256] = z;
    }

    const int arow = t >> 2;
    const int akg  = (t & 3) * 8;
    const float* pA = feat + (size_t)(m0 + arow) * 256;
    const unsigned short* pB = W1T + (size_t)(bn * 256 + t) * 256;

    const int wave = t >> 6, lane = t & 63, l15 = lane & 15, quad = lane >> 4;

    f32x4 acc[4][4];
#pragma unroll
    for (int rm = 0; rm < 4; rm++)
#pragma unroll
        for (int cn = 0; cn < 4; cn++)
            acc[rm][cn] = (f32x4){0.f, 0.f, 0.f, 0.f};

    for (int k0 = 0; k0 < 256; k0 += 32) {
        __syncthreads();
        {
            float4 lo = *(const float4*)(pA + k0 + akg);
            float4 hi = *(const float4*)(pA + k0 + akg + 4);
            union { bf16x8 v; unsigned short s[8]; } u;
            u.s[0] = f2bf(lo.x); u.s[1] = f2bf(lo.y); u.s[2] = f2bf(lo.z); u.s[3] = f2bf(lo.w);
            u.s[4] = f2bf(hi.x); u.s[5] = f2bf(hi.y); u.s[6] = f2bf(hi.z); u.s[7] = f2bf(hi.w);
            *(bf16x8*)(sA + arow * SA_STRIDE + akg) = u.v;
        }
        {
            const unsigned short* p = pB + k0;
            uint4 q0 = *(const uint4*)(p);
            uint4 q1 = *(const uint4*)(p + 8);
            uint4 q2 = *(const uint4*)(p + 16);
            uint4 q3 = *(const uint4*)(p + 24);
            *(uint4*)(sB + t * SB_STRIDE +  0) = q0;
            *(uint4*)(sB + t * SB_STRIDE +  8) = q1;
            *(uint4*)(sB + t * SB_STRIDE + 16) = q2;
            *(uint4*)(sB + t * SB_STRIDE + 24) = q3;
        }
        __syncthreads();

        bf16x8 af[4], bfr[4];
#pragma unroll
        for (int rm = 0; rm < 4; rm++)
            af[rm] = *(const bf16x8*)(sA + (rm * 16 + l15) * SA_STRIDE + quad * 8);
#pragma unroll
        for (int cn = 0; cn < 4; cn++)
            bfr[cn] = *(const bf16x8*)(sB + (wave * 64 + cn * 16 + l15) * SB_STRIDE + quad * 8);
#pragma unroll
        for (int rm = 0; rm < 4; rm++)
#pragma unroll
            for (int cn = 0; cn < 4; cn++)
                acc[rm][cn] = __builtin_amdgcn_mfma_f32_16x16x32_bf16(af[rm], bfr[cn], acc[rm][cn], 0, 0, 0);
    }

#pragma unroll
    for (int cn = 0; cn < 4; cn++) {
        int colh = wave * 64 + cn * 16 + l15;
        float bias = (bn == 0) ? b1[colh] : 0.f;
        int col = bn * 256 + colh;
#pragma unroll
        for (int rm = 0; rm < 4; rm++)
#pragma unroll
            for (int r = 0; r < 4; r++) {
                int row = m0 + rm * 16 + quad * 4 + r;
                P[(size_t)row * 512 + col] = f2bf(acc[rm][cn][r] + bias);
            }
    }
}

// 8 bf16 (u,v) pairs -> partial relu-dot (b1 already folded into u)
__device__ inline float dot8nb(uint4 qu, uint4 qv, const float* w2p) {
    unsigned us[4] = {qu.x, qu.y, qu.z, qu.w};
    unsigned vs[4] = {qv.x, qv.y, qv.z, qv.w};
    float p = 0.f;
#pragma unroll
    for (int j = 0; j < 4; j++) {
        float ulo = __uint_as_float(us[j] << 16);
        float uhi = __uint_as_float(us[j] & 0xffff0000u);
        float vlo = __uint_as_float(vs[j] << 16);
        float vhi = __uint_as_float(vs[j] & 0xffff0000u);
        float hlo = fmaxf(ulo + vlo, 0.f);
        float hhi = fmaxf(uhi + vhi, 0.f);
        p = fmaf(hlo, w2p[2 * j],     p);
        p = fmaf(hhi, w2p[2 * j + 1], p);
    }
    return p;
}

// Bucketed edge scoring: 16-lane worker owns (src bucket, offset o); U'[src]
// register-resident, streams V[dst] (2-stage pipeline), 8 workers per bucket.
__global__ __launch_bounds__(256)
void edge_score(const unsigned short* __restrict__ P,
                const float* __restrict__ W2, const float* __restrict__ b2,
                const int* __restrict__ gCount, const int* __restrict__ gBucket,
                float* __restrict__ out) {
    const int b     = blockIdx.x & 7;          // XCD-aware batch mapping
    const int chunk = blockIdx.x >> 3;         // 0..255 -> srcs {2c, 2c+1}
    const int lane  = threadIdx.x & 63;
    const int wave  = threadIdx.x >> 6;
    const int g     = lane >> 4;
    const int w     = lane & 15;
    const int wid   = wave * 4 + g;            // 0..15
    const int s     = 2 * chunk + (wid >> 3);  // bucket src
    const int o     = wid & 7;                 // worker offset in bucket

    const int en = gCount[s];
    const int* bucket = gBucket + (s << 7);

    float w2r[16];
#pragma unroll
    for (int j = 0; j < 4; j++)
        *(float4*)(w2r + 4 * j) = *(const float4*)(W2 + w * 16 + 4 * j);
    const float b2v = b2[0];

    const unsigned short* Pu = P + ((size_t)b * 512 + s) * 512 + w * 16;
    uint4 u0 = *(const uint4*)(Pu);
    uint4 u1 = *(const uint4*)(Pu + 8);
    const unsigned short* Pv = P + (size_t)b * 512 * 512 + 256 + w * 16;
    float* outb = out + ((size_t)b * 512 + s) * 512;

    int j = o;
    int dst0 = 0; uint4 v00 = {}, v01 = {};
    if (j < en) {
        dst0 = bucket[j];
        const unsigned short* pv = Pv + (size_t)dst0 * 512;
        v00 = *(const uint4*)pv; v01 = *(const uint4*)(pv + 8);
    }
    while (j < en) {
        int jn = j + 8;
        int dst1 = 0; uint4 v10 = {}, v11 = {};
        if (jn < en) {
            dst1 = bucket[jn];
            const unsigned short* pv = Pv + (size_t)dst1 * 512;
            v10 = *(const uint4*)pv; v11 = *(const uint4*)(pv + 8);
        }
        float p = dot8nb(u0, v00, w2r) + dot8nb(u1, v01, w2r + 8);
        p += __shfl_xor(p, 1);
        p += __shfl_xor(p, 2);
        p += __shfl_xor(p, 4);
        p += __shfl_xor(p, 8);
        if (w == 0) {
            float sv = 1.0f / (1.0f + __expf(-(p + b2v)));
            outb[dst0] = sv;
        }
        dst0 = dst1; v00 = v10; v01 = v11; j = jn;
    }
}

extern "C" void kernel_launch(void* const* d_in, const int* in_sizes, int n_in,
                              void* d_out, int out_size, void* d_ws, size_t ws_size,
                              hipStream_t stream) {
    const float* feat = (const float*)d_in[0];
    const float* W1   = (const float*)d_in[1];
    const float* b1   = (const float*)d_in[2];
    const float* W2   = (const float*)d_in[3];
    const float* b2   = (const float*)d_in[4];
    const int*   eidx = (const int*)d_in[5];
    float* out = (float*)d_out;

    unsigned short* W1T = (unsigned short*)d_ws;                        // 256 KB
    unsigned short* P   = (unsigned short*)((char*)d_ws + (1 << 20));   // 4 MB
    int* gCount  = (int*)((char*)d_ws + (6 << 20));                     // 2 KB
    int* gBucket = (int*)((char*)d_ws + (6 << 20) + 4096);              // 256 KB

    prep_k<<<33, 256, 0, stream>>>(W1, W1T, gCount);
    node_gemm<<<192, 256, 0, stream>>>(feat, W1T, b1, eidx, P, (float4*)out, gCount, gBucket);
    edge_score<<<2048, 256, 0, stream>>>(P, W2, b2, gCount, gBucket, out);
}

// Round 7
// 92.266 us; speedup vs baseline: 1.3327x; 1.0541x over previous
//
#include <hip/hip_runtime.h>
#include <hip/hip_bf16.h>
#include <cstdint>

#define B_ 8
#define N_ 512
#define D_ 256
#define E_ 16384
#define H_ 256

#define SA_STRIDE 56
#define SB_STRIDE 56
#define BCAP 128   // bucket capacity (mean 32, max ~55 for E=16384 over 512 srcs)

using bf16x8 = __attribute__((ext_vector_type(8))) short;
using f32x4  = __attribute__((ext_vector_type(4))) float;

__device__ inline unsigned short f2bf(float f) {
    union { float f; unsigned u; } v; v.f = f;
    unsigned u = v.u;
    return (unsigned short)((u + 0x7fffu + ((u >> 16) & 1u)) >> 16);  // RNE
}

// blocks 0-31: transpose W1 halves -> W1T (512 n-rows x 256 k) bf16.
// block 32: zero the 512 bucket counters (runs before node_gemm via stream order).
__global__ __launch_bounds__(256)
void prep_k(const float* __restrict__ W1, unsigned short* __restrict__ W1T,
            int* __restrict__ gCount) {
    __shared__ float tile[64][65];
    const int tb = blockIdx.x, t = threadIdx.x;
    if (tb == 32) {
        gCount[t] = 0;
        gCount[t + 256] = 0;
        return;
    }
    const int h   = tb >> 4;
    const int rem = tb & 15;
    const int tk  = (rem >> 2) * 64;
    const int tn  = (rem & 3) * 64;
    const float* Wh = W1 + (size_t)h * 256 * 256;
    const int c = t & 63, r0 = t >> 6;
#pragma unroll
    for (int i = 0; i < 16; i++) {
        int r = r0 + i * 4;
        tile[r][c] = Wh[(size_t)(tk + r) * 256 + tn + c];
    }
    __syncthreads();
#pragma unroll
    for (int i = 0; i < 16; i++) {
        int rn = r0 + i * 4;
        W1T[(size_t)(h * 256 + tn + rn) * 256 + tk + c] = f2bf(tile[c][rn]);
    }
}

// blocks 0-127: P (4096,512) bf16 = feat x [W1a|W1b], b1 folded into U half;
//               also zeroes d_out (64 KB per block).
// blocks 128-135: LDS-aggregated bucket scatter (2048 edges/block):
//   slot via LDS histogram atomic, ONE global atomicAdd per (block,src) range
//   reservation (<=4096 global atomics total, <=8-way contention) — R6's
//   16384 same-line global atomics cost ~25 us.
__global__ __launch_bounds__(256)
void node_gemm(const float* __restrict__ feat,
               const unsigned short* __restrict__ W1T,
               const float* __restrict__ b1,
               const int* __restrict__ eidx,
               unsigned short* __restrict__ P,
               float4* __restrict__ out4,
               int* __restrict__ gCount, int* __restrict__ gBucket) {
    const int t = threadIdx.x;

    if (blockIdx.x >= 128) {
        __shared__ int hist[512];
        __shared__ int base[512];
        const int sb = blockIdx.x - 128;
        int mysrc[8], mydst[8], myslot[8];
        for (int i = t; i < 512; i += 256) hist[i] = 0;
        __syncthreads();
#pragma unroll
        for (int i = 0; i < 8; i++) {
            int e = sb * 2048 + i * 256 + t;
            mysrc[i] = eidx[e];
            mydst[i] = eidx[E_ + e];
            myslot[i] = atomicAdd(&hist[mysrc[i]], 1);
        }
        __syncthreads();
        for (int i = t; i < 512; i += 256) {
            int c = hist[i];
            base[i] = c ? atomicAdd(&gCount[i], c) : 0;
        }
        __syncthreads();
#pragma unroll
        for (int i = 0; i < 8; i++)
            gBucket[(mysrc[i] << 7) + base[mysrc[i]] + myslot[i]] = mydst[i];
        return;
    }

    __shared__ unsigned short sA[64 * SA_STRIDE];
    __shared__ unsigned short sB[256 * SB_STRIDE];

    const int bm = blockIdx.x >> 1;
    const int bn = blockIdx.x & 1;
    const int m0 = bm * 64;

    {
        float4 z = make_float4(0.f, 0.f, 0.f, 0.f);
        float4* oz = out4 + (size_t)blockIdx.x * 4096 + t;
#pragma unroll
        for (int i = 0; i < 16; i++) oz[i * 256] = z;
    }

    const int arow = t >> 2;
    const int akg  = (t & 3) * 8;
    const float* pA = feat + (size_t)(m0 + arow) * 256;
    const unsigned short* pB = W1T + (size_t)(bn * 256 + t) * 256;

    const int wave = t >> 6, lane = t & 63, l15 = lane & 15, quad = lane >> 4;

    f32x4 acc[4][4];
#pragma unroll
    for (int rm = 0; rm < 4; rm++)
#pragma unroll
        for (int cn = 0; cn < 4; cn++)
            acc[rm][cn] = (f32x4){0.f, 0.f, 0.f, 0.f};

    for (int k0 = 0; k0 < 256; k0 += 32) {
        __syncthreads();
        {
            float4 lo = *(const float4*)(pA + k0 + akg);
            float4 hi = *(const float4*)(pA + k0 + akg + 4);
            union { bf16x8 v; unsigned short s[8]; } u;
            u.s[0] = f2bf(lo.x); u.s[1] = f2bf(lo.y); u.s[2] = f2bf(lo.z); u.s[3] = f2bf(lo.w);
            u.s[4] = f2bf(hi.x); u.s[5] = f2bf(hi.y); u.s[6] = f2bf(hi.z); u.s[7] = f2bf(hi.w);
            *(bf16x8*)(sA + arow * SA_STRIDE + akg) = u.v;
        }
        {
            const unsigned short* p = pB + k0;
            uint4 q0 = *(const uint4*)(p);
            uint4 q1 = *(const uint4*)(p + 8);
            uint4 q2 = *(const uint4*)(p + 16);
            uint4 q3 = *(const uint4*)(p + 24);
            *(uint4*)(sB + t * SB_STRIDE +  0) = q0;
            *(uint4*)(sB + t * SB_STRIDE +  8) = q1;
            *(uint4*)(sB + t * SB_STRIDE + 16) = q2;
            *(uint4*)(sB + t * SB_STRIDE + 24) = q3;
        }
        __syncthreads();

        bf16x8 af[4], bfr[4];
#pragma unroll
        for (int rm = 0; rm < 4; rm++)
            af[rm] = *(const bf16x8*)(sA + (rm * 16 + l15) * SA_STRIDE + quad * 8);
#pragma unroll
        for (int cn = 0; cn < 4; cn++)
            bfr[cn] = *(const bf16x8*)(sB + (wave * 64 + cn * 16 + l15) * SB_STRIDE + quad * 8);
#pragma unroll
        for (int rm = 0; rm < 4; rm++)
#pragma unroll
            for (int cn = 0; cn < 4; cn++)
                acc[rm][cn] = __builtin_amdgcn_mfma_f32_16x16x32_bf16(af[rm], bfr[cn], acc[rm][cn], 0, 0, 0);
    }

#pragma unroll
    for (int cn = 0; cn < 4; cn++) {
        int colh = wave * 64 + cn * 16 + l15;
        float bias = (bn == 0) ? b1[colh] : 0.f;
        int col = bn * 256 + colh;
#pragma unroll
        for (int rm = 0; rm < 4; rm++)
#pragma unroll
            for (int r = 0; r < 4; r++) {
                int row = m0 + rm * 16 + quad * 4 + r;
                P[(size_t)row * 512 + col] = f2bf(acc[rm][cn][r] + bias);
            }
    }
}

// 8 bf16 (u,v) pairs -> partial relu-dot (b1 already folded into u)
__device__ inline float dot8nb(uint4 qu, uint4 qv, const float* w2p) {
    unsigned us[4] = {qu.x, qu.y, qu.z, qu.w};
    unsigned vs[4] = {qv.x, qv.y, qv.z, qv.w};
    float p = 0.f;
#pragma unroll
    for (int j = 0; j < 4; j++) {
        float ulo = __uint_as_float(us[j] << 16);
        float uhi = __uint_as_float(us[j] & 0xffff0000u);
        float vlo = __uint_as_float(vs[j] << 16);
        float vhi = __uint_as_float(vs[j] & 0xffff0000u);
        float hlo = fmaxf(ulo + vlo, 0.f);
        float hhi = fmaxf(uhi + vhi, 0.f);
        p = fmaf(hlo, w2p[2 * j],     p);
        p = fmaf(hhi, w2p[2 * j + 1], p);
    }
    return p;
}

// Bucketed edge scoring: 16-lane worker owns (src bucket, offset o); U'[src]
// register-resident, streams V[dst] (2-stage pipeline), 8 workers per bucket.
__global__ __launch_bounds__(256)
void edge_score(const unsigned short* __restrict__ P,
                const float* __restrict__ W2, const float* __restrict__ b2,
                const int* __restrict__ gCount, const int* __restrict__ gBucket,
                float* __restrict__ out) {
    const int b     = blockIdx.x & 7;          // XCD-aware batch mapping
    const int chunk = blockIdx.x >> 3;         // 0..255 -> srcs {2c, 2c+1}
    const int lane  = threadIdx.x & 63;
    const int wave  = threadIdx.x >> 6;
    const int g     = lane >> 4;
    const int w     = lane & 15;
    const int wid   = wave * 4 + g;            // 0..15
    const int s     = 2 * chunk + (wid >> 3);  // bucket src
    const int o     = wid & 7;                 // worker offset in bucket

    const int en = gCount[s];
    const int* bucket = gBucket + (s << 7);

    float w2r[16];
#pragma unroll
    for (int j = 0; j < 4; j++)
        *(float4*)(w2r + 4 * j) = *(const float4*)(W2 + w * 16 + 4 * j);
    const float b2v = b2[0];

    const unsigned short* Pu = P + ((size_t)b * 512 + s) * 512 + w * 16;
    uint4 u0 = *(const uint4*)(Pu);
    uint4 u1 = *(const uint4*)(Pu + 8);
    const unsigned short* Pv = P + (size_t)b * 512 * 512 + 256 + w * 16;
    float* outb = out + ((size_t)b * 512 + s) * 512;

    int j = o;
    int dst0 = 0; uint4 v00 = {}, v01 = {};
    if (j < en) {
        dst0 = bucket[j];
        const unsigned short* pv = Pv + (size_t)dst0 * 512;
        v00 = *(const uint4*)pv; v01 = *(const uint4*)(pv + 8);
    }
    while (j < en) {
        int jn = j + 8;
        int dst1 = 0; uint4 v10 = {}, v11 = {};
        if (jn < en) {
            dst1 = bucket[jn];
            const unsigned short* pv = Pv + (size_t)dst1 * 512;
            v10 = *(const uint4*)pv; v11 = *(const uint4*)(pv + 8);
        }
        float p = dot8nb(u0, v00, w2r) + dot8nb(u1, v01, w2r + 8);
        p += __shfl_xor(p, 1);
        p += __shfl_xor(p, 2);
        p += __shfl_xor(p, 4);
        p += __shfl_xor(p, 8);
        if (w == 0) {
            float sv = 1.0f / (1.0f + __expf(-(p + b2v)));
            outb[dst0] = sv;
        }
        dst0 = dst1; v00 = v10; v01 = v11; j = jn;
    }
}

extern "C" void kernel_launch(void* const* d_in, const int* in_sizes, int n_in,
                              void* d_out, int out_size, void* d_ws, size_t ws_size,
                              hipStream_t stream) {
    const float* feat = (const float*)d_in[0];
    const float* W1   = (const float*)d_in[1];
    const float* b1   = (const float*)d_in[2];
    const float* W2   = (const float*)d_in[3];
    const float* b2   = (const float*)d_in[4];
    const int*   eidx = (const int*)d_in[5];
    float* out = (float*)d_out;

    unsigned short* W1T = (unsigned short*)d_ws;                        // 256 KB
    unsigned short* P   = (unsigned short*)((char*)d_ws + (1 << 20));   // 4 MB
    int* gCount  = (int*)((char*)d_ws + (6 << 20));                     // 2 KB
    int* gBucket = (int*)((char*)d_ws + (6 << 20) + 4096);              // 256 KB

    prep_k<<<33, 256, 0, stream>>>(W1, W1T, gCount);
    node_gemm<<<136, 256, 0, stream>>>(feat, W1T, b1, eidx, P, (float4*)out, gCount, gBucket);
    edge_score<<<2048, 256, 0, stream>>>(P, W2, b2, gCount, gBucket, out);
}